// Round 5
// baseline (659.990 us; speedup 1.0000x reference)
//
#include <hip/hip_runtime.h>
#include <math.h>

// ROUND-5 DIAGNOSTIC BUILD: K-loop executed twice (second pass into pinned
// dummy accumulators). dur(gate) - 310us == marginal cost of one K-loop.
// Outputs are bit-identical to R4. Score regression this round is intentional.

// N=16384, D=4096, E=256, TOPK=6, scale=1.5
constexpr int D     = 4096;
constexpr int D4    = 1024;     // float4 per row
constexpr int E     = 256;
constexpr int TK    = 6;
constexpr int BM    = 64;       // rows per block
constexpr int NT    = 1024;     // 16 waves = 4 waves/SIMD
constexpr int CK    = 512;      // k-chunk staged in LDS
constexpr int NCH   = D / CK;   // 8 chunks
constexpr int NST   = CK / 32;  // 16 subtiles per chunk
constexpr float TAU = 3e-5f;    // ambiguity threshold

typedef __attribute__((ext_vector_type(8)))  short short8;
typedef __attribute__((ext_vector_type(16))) float float16;
typedef unsigned short ushort_t;

__device__ __forceinline__ ushort_t f2bf(float f) {  // RTNE fp32->bf16
  unsigned u = __float_as_uint(f);
  return (ushort_t)((u + 0x7fffu + ((u >> 16) & 1u)) >> 16);
}
__device__ __forceinline__ float bf2f(ushort_t h) {
  return __uint_as_float(((unsigned)h) << 16);
}

// 16 waves: wave (eg, kh) = 64 rows x experts [32eg,32eg+32), k-half kh.
// K-loop is BARRIER-FREE per subtile: B read direct global->reg from the
// tile-major repacked W' (coalesced 16B/lane); A read from LDS chunk staged
// once per 512 k (2 barriers per chunk).
struct __align__(16) SMem {
  union {
    struct {                        // 128 KB: A2[row][plane][512] bf16
      ushort_t A2[BM * 1024];       // row stride 1024 el; +512 = lo plane
    } st;
    struct {                        // epilogue (staging dead)
      float red[8][2][16][64];      // kh-pair accumulator reduction, 64 KB
      float val[BM * 65];
      int   id [BM * 65];
    } ep;
  } u;
  float  bias[E];
  int    nflag;
  int    flagrow[BM];
  int    flagid[BM][8];
  double exact[8];
};
static_assert(sizeof(SMem) <= 160 * 1024, "LDS overflow");

// ---------- prepass: W fp32 -> bf16 hi/lo, TILE-MAJOR [kt][e][32] ----------
__global__ __launch_bounds__(256)
void conv_w(const float* __restrict__ wg, ushort_t* __restrict__ whi,
            ushort_t* __restrict__ wlo)
{
  size_t i = (size_t)blockIdx.x * 256 + threadIdx.x;   // over E*D/4
  const int e  = (int)(i >> 10);          // i*4 / D
  const int k4 = (int)(i & 1023);
  const int kt = k4 >> 3;                 // k/32
  const int kw = (k4 & 7) * 4;            // k%32
  float4 v = ((const float4*)wg)[i];
  float a[4] = {v.x, v.y, v.z, v.w};
  ushort_t h[4], l[4];
#pragma unroll
  for (int j = 0; j < 4; ++j) {
    h[j] = f2bf(a[j]);
    l[j] = f2bf(a[j] - bf2f(h[j]));
  }
  const size_t dst = (size_t)kt * (E * 32) + e * 32 + kw;
  *(uint2*)&whi[dst] = *(uint2*)h;
  *(uint2*)&wlo[dst] = *(uint2*)l;
}

// ---------- main fused kernel ----------
__global__ __launch_bounds__(NT, 4)
void gate_kernel(const float* __restrict__ xg, const float* __restrict__ wg,
                 const float* __restrict__ bg,
                 const ushort_t* __restrict__ whi, const ushort_t* __restrict__ wlo,
                 float* __restrict__ outw, float* __restrict__ outi)
{
  __shared__ SMem sm;
  const int t    = threadIdx.x;
  const int row0 = blockIdx.x * BM;
  const int wv   = t >> 6;       // 0..15
  const int lane = t & 63;
  const int m    = lane & 31;
  const int hf   = lane >> 5;
  const int eg   = wv >> 1;      // 0..7 expert group (32 experts)
  const int kh   = wv & 1;       // k-half of each 32-k tile

  if (t < E) sm.bias[t] = bg[t];
  if (t == 0) sm.nflag = 0;

  const float4* x4 = (const float4*)xg;
  const float4* w4 = (const float4*)wg;

  float16 acc0, acc1;            // rows 0-31 / 32-63 x 32 experts (k-half)
#pragma unroll
  for (int i = 0; i < 16; ++i) { acc0[i] = 0.f; acc1[i] = 0.f; }

  // A staging roles: row = t>>4, float4-column kc = t&15 (8 f4 per thread)
  const int a_row = t >> 4;
  const int kc    = t & 15;

  // A fragment read bases (swizzled)
  const int q  = kh * 2 + hf;
  const int b2 = (m >> 2) & 1;
  const ushort_t* a0P = &sm.u.st.A2[m        * 1024 + ((q ^ (m & 3)) << 3)];
  const ushort_t* a1P = &sm.u.st.A2[(32 + m) * 1024 + ((q ^ (m & 3)) << 3)];

  // B direct-load base (tile-major W'): elem = kt*8192 + e*32 + kh*16 + hf*8
  const size_t bOff = (size_t)(eg * 32 + m) * 32 + kh * 16 + hf * 8;

  auto stage_A = [&](int c) {
    const float4* src = x4 + (size_t)(row0 + a_row) * D4 + c * 128 + kc;
#pragma unroll
    for (int j = 0; j < 8; ++j) {
      float4 v = src[j * 16];
      float a[4] = {v.x, v.y, v.z, v.w};
      ushort_t h[4], l[4];
#pragma unroll
      for (int i = 0; i < 4; ++i) {
        h[i] = f2bf(a[i]);
        l[i] = f2bf(a[i] - bf2f(h[i]));
      }
      const int slot = j * 8 + (kc >> 1);
      const int half = kc & 1;
      const int sw   = ((slot ^ (a_row & 7)) << 3) + half * 4;
      *(uint2*)&sm.u.st.A2[a_row * 1024 + sw]       = *(uint2*)h;
      *(uint2*)&sm.u.st.A2[a_row * 1024 + 512 + sw] = *(uint2*)l;
    }
  };

  // ---- K loop pass 1 (REAL): 8 chunks x 16 barrier-free subtiles ----
  for (int c = 0; c < NCH; ++c) {
    __syncthreads();                       // prev chunk's A reads complete
    stage_A(c);
    __syncthreads();                       // A chunk published

    const ushort_t* bH = whi + (size_t)(c * NST) * 8192 + bOff;
    const ushort_t* bL = wlo + (size_t)(c * NST) * 8192 + bOff;
#pragma unroll 4
    for (int s = 0; s < NST; ++s) {
      short8 bh = *(const short8*)(bH + (size_t)s * 8192);
      short8 bl = *(const short8*)(bL + (size_t)s * 8192);
      const int ao = (s ^ b2) << 5;
      short8 a0h = *(const short8*)(a0P + ao);
      short8 a0l = *(const short8*)(a0P + 512 + ao);
      short8 a1h = *(const short8*)(a1P + ao);
      short8 a1l = *(const short8*)(a1P + 512 + ao);
      acc0 = __builtin_amdgcn_mfma_f32_32x32x16_bf16(a0h, bh, acc0, 0, 0, 0);
      acc0 = __builtin_amdgcn_mfma_f32_32x32x16_bf16(a0h, bl, acc0, 0, 0, 0);
      acc0 = __builtin_amdgcn_mfma_f32_32x32x16_bf16(a0l, bh, acc0, 0, 0, 0);
      acc1 = __builtin_amdgcn_mfma_f32_32x32x16_bf16(a1h, bh, acc1, 0, 0, 0);
      acc1 = __builtin_amdgcn_mfma_f32_32x32x16_bf16(a1h, bl, acc1, 0, 0, 0);
      acc1 = __builtin_amdgcn_mfma_f32_32x32x16_bf16(a1l, bh, acc1, 0, 0, 0);
    }
  }

  // ---- K loop pass 2 (DIAGNOSTIC DUMMY, identical work, pinned) ----
  {
    float16 accd0, accd1;
#pragma unroll
    for (int i = 0; i < 16; ++i) { accd0[i] = 0.f; accd1[i] = 0.f; }
    for (int c = 0; c < NCH; ++c) {
      __syncthreads();
      stage_A(c);
      __syncthreads();

      const ushort_t* bH = whi + (size_t)(c * NST) * 8192 + bOff;
      const ushort_t* bL = wlo + (size_t)(c * NST) * 8192 + bOff;
#pragma unroll 4
      for (int s = 0; s < NST; ++s) {
        short8 bh = *(const short8*)(bH + (size_t)s * 8192);
        short8 bl = *(const short8*)(bL + (size_t)s * 8192);
        const int ao = (s ^ b2) << 5;
        short8 a0h = *(const short8*)(a0P + ao);
        short8 a0l = *(const short8*)(a0P + 512 + ao);
        short8 a1h = *(const short8*)(a1P + ao);
        short8 a1l = *(const short8*)(a1P + 512 + ao);
        accd0 = __builtin_amdgcn_mfma_f32_32x32x16_bf16(a0h, bh, accd0, 0, 0, 0);
        accd0 = __builtin_amdgcn_mfma_f32_32x32x16_bf16(a0h, bl, accd0, 0, 0, 0);
        accd0 = __builtin_amdgcn_mfma_f32_32x32x16_bf16(a0l, bh, accd0, 0, 0, 0);
        accd1 = __builtin_amdgcn_mfma_f32_32x32x16_bf16(a1h, bh, accd1, 0, 0, 0);
        accd1 = __builtin_amdgcn_mfma_f32_32x32x16_bf16(a1h, bl, accd1, 0, 0, 0);
        accd1 = __builtin_amdgcn_mfma_f32_32x32x16_bf16(a1l, bh, accd1, 0, 0, 0);
      }
    }
    // keep the dummy pass live without affecting results (rule #17)
    float fd = 0.f;
#pragma unroll
    for (int i = 0; i < 16; ++i) fd += accd0[i] + accd1[i];
    asm volatile("" :: "v"(fd));
  }

  __syncthreads();                         // A2 dead; union reuse safe

  // ---- kh-pair accumulator reduction through LDS ----
  if (kh == 1) {
#pragma unroll
    for (int r = 0; r < 16; ++r) {
      sm.u.ep.red[eg][0][r][lane] = acc0[r];
      sm.u.ep.red[eg][1][r][lane] = acc1[r];
    }
  }
  __syncthreads();
  if (kh == 0) {
#pragma unroll
    for (int r = 0; r < 16; ++r) {
      acc0[r] += sm.u.ep.red[eg][0][r][lane];
      acc1[r] += sm.u.ep.red[eg][1][r][lane];
    }
  }

  // ---- per-group top-8 over 32 experts, per row (kh==0 waves only) ----
  const int myE = eg * 32 + m;
  const float myBias = sm.bias[myE];

  if (kh == 0) {
#pragma unroll
    for (int b = 0; b < 2; ++b) {
#pragma unroll
      for (int reg = 0; reg < 16; ++reg) {
        const int row_local = b * 32 + (reg & 3) + 8 * (reg >> 2) + 4 * hf;
        float s = b ? acc1[reg] : acc0[reg];
        float v = sqrtf(fmaxf(s, 0.f) + log1pf(expf(-fabsf(s)))) + myBias;
#pragma unroll
        for (int ssel = 0; ssel < 8; ++ssel) {
          float bv = v;
#pragma unroll
          for (int off = 1; off < 32; off <<= 1)
            bv = fmaxf(bv, __shfl_xor(bv, off, 64));
          unsigned long long ball = __ballot(v == bv);
          unsigned hm = (unsigned)(ball >> (hf * 32));
          int mwin = __ffs(hm) - 1;            // lowest expert wins ties
          if (m == mwin) {
            sm.u.ep.val[row_local * 65 + eg * 8 + ssel] = v;
            sm.u.ep.id [row_local * 65 + eg * 8 + ssel] = myE;
            v = -INFINITY;
          }
        }
      }
    }
  }
  __syncthreads();

  // ---- merge 8x8 -> global top-8 per row; flag ambiguous rows ----
  if (t < 512) {
    const int r = t >> 3, g = t & 7;
    float mv[8]; int mi[8];
#pragma unroll
    for (int q2 = 0; q2 < 8; ++q2) {
      mv[q2] = sm.u.ep.val[r * 65 + q2 * 8 + g];
      mi[q2] = sm.u.ep.id [r * 65 + q2 * 8 + g];
    }
    float tv[8]; int ti[8];
#pragma unroll
    for (int s = 0; s < 8; ++s) {
      float bv = mv[0]; int bi = mi[0];
#pragma unroll
      for (int q2 = 1; q2 < 8; ++q2)
        if (mv[q2] > bv || (mv[q2] == bv && mi[q2] < bi)) { bv = mv[q2]; bi = mi[q2]; }
#pragma unroll
      for (int off = 1; off < 8; off <<= 1) {
        float ov = __shfl_xor(bv, off, 64);
        int   oi = __shfl_xor(bi, off, 64);
        if (ov > bv || (ov == bv && oi < bi)) { bv = ov; bi = oi; }
      }
      tv[s] = bv; ti[s] = bi;
#pragma unroll
      for (int q2 = 0; q2 < 8; ++q2)
        if (mi[q2] == bi) mv[q2] = -INFINITY;
    }
    if (g == 0) {
      bool flag = false;
#pragma unroll
      for (int i = 0; i < 7; ++i) flag |= (tv[i] - tv[i + 1] < TAU);
      const int grow = row0 + r;
      if (!flag) {
        float og[6], ssum = 0.f;
#pragma unroll
        for (int i = 0; i < 6; ++i) { og[i] = tv[i] - sm.bias[ti[i]]; ssum += og[i]; }
        const float sc = 1.5f / ssum;
#pragma unroll
        for (int i = 0; i < 6; ++i) {
          outw[(size_t)grow * TK + i] = og[i] * sc;
          outi[(size_t)grow * TK + i] = (float)ti[i];
        }
      } else {
        int slot = atomicAdd(&sm.nflag, 1);
        sm.flagrow[slot] = grow;
#pragma unroll
        for (int i = 0; i < 8; ++i) sm.flagid[slot][i] = ti[i];
      }
    }
  }
  __syncthreads();

  // ---- exact fp64 rescue for flagged rows (expected <1/block) ----
  const int nf = sm.nflag;
  for (int f = 0; f < nf; ++f) {
    const int grow = sm.flagrow[f];
    if (wv < 8) {
      const int e = sm.flagid[f][wv];
      double accd = 0.0;
      const float4* xr = x4 + (size_t)grow * D4 + lane * 16;
      const float4* wr = w4 + (size_t)e    * D4 + lane * 16;
#pragma unroll
      for (int i = 0; i < 16; ++i) {
        float4 xv = xr[i], wl = wr[i];
        accd = fma((double)xv.x, (double)wl.x, accd);
        accd = fma((double)xv.y, (double)wl.y, accd);
        accd = fma((double)xv.z, (double)wl.z, accd);
        accd = fma((double)xv.w, (double)wl.w, accd);
      }
#pragma unroll
      for (int off = 1; off < 64; off <<= 1)
        accd += __shfl_xor(accd, off, 64);
      if (lane == 0) {
        double sp = fmax(accd, 0.0) + log1p(exp(-fabs(accd)));
        sm.exact[wv] = sqrt(sp);   // orig (unbiased) score
      }
    }
    __syncthreads();
    if (t == 0) {
      double ov[8]; int oid[8], ordr[8];
      for (int i = 0; i < 8; ++i) { ov[i] = sm.exact[i]; oid[i] = sm.flagid[f][i]; ordr[i] = i; }
      for (int i = 0; i < 6; ++i) {
        int b = i;
        for (int j = i + 1; j < 8; ++j) {
          double bj = ov[ordr[j]] + (double)sm.bias[oid[ordr[j]]];
          double bb = ov[ordr[b]] + (double)sm.bias[oid[ordr[b]]];
          if (bj > bb || (bj == bb && oid[ordr[j]] < oid[ordr[b]])) b = j;
        }
        int tmp = ordr[i]; ordr[i] = ordr[b]; ordr[b] = tmp;
      }
      double ssum = 0.0;
      for (int i = 0; i < 6; ++i) ssum += ov[ordr[i]];
      double sc = 1.5 / ssum;
      for (int i = 0; i < 6; ++i) {
        outw[(size_t)grow * TK + i] = (float)(ov[ordr[i]] * sc);
        outi[(size_t)grow * TK + i] = (float)oid[ordr[i]];
      }
    }
    __syncthreads();
  }
}

extern "C" void kernel_launch(void* const* d_in, const int* in_sizes, int n_in,
                              void* d_out, int out_size, void* d_ws, size_t ws_size,
                              hipStream_t stream) {
  const float* x = (const float*)d_in[0];
  const float* w = (const float*)d_in[1];
  const float* b = (const float*)d_in[2];
  float* out  = (float*)d_out;
  const int N = in_sizes[0] / D;          // 16384

  ushort_t* whi = (ushort_t*)d_ws;                      // E*D bf16 = 2 MB (tile-major)
  ushort_t* wlo = whi + (size_t)E * D;                  // +2 MB

  float* outw = out;                      // [N,6] weights
  float* outi = out + (size_t)N * TK;     // [N,6] indices (as float)

  hipLaunchKernelGGL(conv_w, dim3(E * D / 4 / 256), dim3(256), 0, stream,
                     w, whi, wlo);
  hipLaunchKernelGGL(gate_kernel, dim3(N / BM), dim3(NT), 0, stream,
                     x, w, b, whi, wlo, outw, outi);
}

// Round 7
// 497.863 us; speedup vs baseline: 1.3256x; 1.3256x over previous
//
#include <hip/hip_runtime.h>
#include <math.h>

// N=16384, D=4096, E=256, TOPK=6, scale=1.5
constexpr int D     = 4096;
constexpr int D4    = 1024;     // float4 per row
constexpr int E     = 256;
constexpr int TK    = 6;
constexpr int BM    = 64;       // rows per block
constexpr int NT    = 1024;     // 16 waves = 4 waves/SIMD
constexpr int CK    = 512;      // k-chunk staged in LDS
constexpr int NCH   = D / CK;   // 8 chunks
constexpr int NST   = CK / 32;  // 16 subtiles per chunk
constexpr int VST   = 260;      // val row stride (floats): 4-bank row skew
constexpr float TAU = 3e-5f;    // ambiguity threshold

typedef __attribute__((ext_vector_type(8)))  short short8;
typedef __attribute__((ext_vector_type(16))) float float16;
typedef unsigned short ushort_t;
typedef unsigned long long u64;

__device__ __forceinline__ ushort_t f2bf(float f) {  // RTNE fp32->bf16
  unsigned u = __float_as_uint(f);
  return (ushort_t)((u + 0x7fffu + ((u >> 16) & 1u)) >> 16);
}
__device__ __forceinline__ float bf2f(ushort_t h) {
  return __uint_as_float(((unsigned)h) << 16);
}

// sortable key: (monotone f32 transform << 32) | (255 - idx)
// key order == (value desc, index asc) exactly; idx unique -> keys unique
__device__ __forceinline__ u64 mkkey(float v, int idx) {
  unsigned u = __float_as_uint(v);
  u = ((int)u < 0) ? ~u : (u | 0x80000000u);
  return ((u64)u << 32) | (unsigned)(255 - idx);
}
__device__ __forceinline__ float keyval(u64 k) {
  unsigned u = (unsigned)(k >> 32);
  return __uint_as_float((u & 0x80000000u) ? (u & 0x7FFFFFFFu) : ~u);
}
__device__ __forceinline__ int keyidx(u64 k) {
  return 255 - (int)(unsigned)(k & 0xFFFFFFFFu);
}
__device__ __forceinline__ u64 kmax(u64 a, u64 b) { return a < b ? b : a; }

// compare-exchange: larger key to lower index (descending)
#define CEK(i, j) do { u64 _a = k[i], _b = k[j]; bool _p = _a < _b;          \
                       k[i] = _p ? _b : _a; k[j] = _p ? _a : _b; } while (0)
// Batcher odd-even mergesort, 8 elems at base b (19 CE), descending
#define SORT8(b) do {                                                        \
  CEK(b+0,b+1); CEK(b+2,b+3); CEK(b+4,b+5); CEK(b+6,b+7);                    \
  CEK(b+0,b+2); CEK(b+1,b+3); CEK(b+4,b+6); CEK(b+5,b+7);                    \
  CEK(b+1,b+2); CEK(b+5,b+6);                                                \
  CEK(b+0,b+4); CEK(b+1,b+5); CEK(b+2,b+6); CEK(b+3,b+7);                    \
  CEK(b+2,b+4); CEK(b+3,b+5);                                                \
  CEK(b+1,b+2); CEK(b+3,b+4); CEK(b+5,b+6); } while (0)
// bitonic merge of bitonic k[0..7] -> descending (12 CE)
#define BMERGE8 do {                                                         \
  CEK(0,4); CEK(1,5); CEK(2,6); CEK(3,7);                                    \
  CEK(0,2); CEK(1,3); CEK(4,6); CEK(5,7);                                    \
  CEK(0,1); CEK(2,3); CEK(4,5); CEK(6,7); } while (0)

// 16 waves: wave (eg, kh) = 64 rows x experts [32eg,32eg+32), k-half kh.
// K-loop identical to R4 (measured 122us marginal). Epilogue: sort-network
// top-8 (VALU + 32 independent shuffles) replaces serial shfl extraction.
struct __align__(16) SMem {
  union {
    struct {                        // 128 KB: A2[row][plane][512] bf16
      ushort_t A2[BM * 1024];       // row stride 1024 el; +512 = lo plane
    } st;
    struct {                        // epilogue (staging dead): 129 KB
      float red[8][2][16][64];      // kh-pair accumulator reduction, 64 KB
      float val[BM * VST];          // biased scores [row][expert], 65 KB
    } ep;
  } u;
  float  bias[E];
  int    nflag;
  int    flagrow[BM];
  int    flagid[BM][8];
  double exact[8];
};
static_assert(sizeof(SMem) <= 160 * 1024, "LDS overflow");

// ---------- prepass: W fp32 -> bf16 hi/lo, TILE-MAJOR [kt][e][32] ----------
__global__ __launch_bounds__(256)
void conv_w(const float* __restrict__ wg, ushort_t* __restrict__ whi,
            ushort_t* __restrict__ wlo)
{
  size_t i = (size_t)blockIdx.x * 256 + threadIdx.x;   // over E*D/4
  const int e  = (int)(i >> 10);          // i*4 / D
  const int k4 = (int)(i & 1023);
  const int kt = k4 >> 3;                 // k/32
  const int kw = (k4 & 7) * 4;            // k%32
  float4 v = ((const float4*)wg)[i];
  float a[4] = {v.x, v.y, v.z, v.w};
  ushort_t h[4], l[4];
#pragma unroll
  for (int j = 0; j < 4; ++j) {
    h[j] = f2bf(a[j]);
    l[j] = f2bf(a[j] - bf2f(h[j]));
  }
  const size_t dst = (size_t)kt * (E * 32) + e * 32 + kw;
  *(uint2*)&whi[dst] = *(uint2*)h;
  *(uint2*)&wlo[dst] = *(uint2*)l;
}

// ---------- main fused kernel ----------
__global__ __launch_bounds__(NT, 4)
void gate_kernel(const float* __restrict__ xg, const float* __restrict__ wg,
                 const float* __restrict__ bg,
                 const ushort_t* __restrict__ whi, const ushort_t* __restrict__ wlo,
                 float* __restrict__ outw, float* __restrict__ outi)
{
  __shared__ SMem sm;
  const int t    = threadIdx.x;
  const int row0 = blockIdx.x * BM;
  const int wv   = t >> 6;       // 0..15
  const int lane = t & 63;
  const int m    = lane & 31;
  const int hf   = lane >> 5;
  const int eg   = wv >> 1;      // 0..7 expert group (32 experts)
  const int kh   = wv & 1;       // k-half of each 32-k tile

  if (t < E) sm.bias[t] = bg[t];
  if (t == 0) sm.nflag = 0;

  const float4* x4 = (const float4*)xg;
  const float4* w4 = (const float4*)wg;

  float16 acc0, acc1;            // rows 0-31 / 32-63 x 32 experts (k-half)
#pragma unroll
  for (int i = 0; i < 16; ++i) { acc0[i] = 0.f; acc1[i] = 0.f; }

  // A staging roles: row = t>>4, float4-column kc = t&15 (8 f4 per thread)
  const int a_row = t >> 4;
  const int kc    = t & 15;

  // A fragment read bases (swizzled)
  const int q  = kh * 2 + hf;
  const int b2 = (m >> 2) & 1;
  const ushort_t* a0P = &sm.u.st.A2[m        * 1024 + ((q ^ (m & 3)) << 3)];
  const ushort_t* a1P = &sm.u.st.A2[(32 + m) * 1024 + ((q ^ (m & 3)) << 3)];

  // B direct-load base (tile-major W'): elem = kt*8192 + e*32 + kh*16 + hf*8
  const size_t bOff = (size_t)(eg * 32 + m) * 32 + kh * 16 + hf * 8;

  auto stage_A = [&](int c) {
    const float4* src = x4 + (size_t)(row0 + a_row) * D4 + c * 128 + kc;
#pragma unroll
    for (int j = 0; j < 8; ++j) {
      float4 v = src[j * 16];
      float a[4] = {v.x, v.y, v.z, v.w};
      ushort_t h[4], l[4];
#pragma unroll
      for (int i = 0; i < 4; ++i) {
        h[i] = f2bf(a[i]);
        l[i] = f2bf(a[i] - bf2f(h[i]));
      }
      const int slot = j * 8 + (kc >> 1);
      const int half = kc & 1;
      const int sw   = ((slot ^ (a_row & 7)) << 3) + half * 4;
      *(uint2*)&sm.u.st.A2[a_row * 1024 + sw]       = *(uint2*)h;
      *(uint2*)&sm.u.st.A2[a_row * 1024 + 512 + sw] = *(uint2*)l;
    }
  };

  // ---- K loop: 8 chunks x 16 barrier-free subtiles (identical to R4) ----
  for (int c = 0; c < NCH; ++c) {
    __syncthreads();                       // prev chunk's A reads complete
    stage_A(c);
    __syncthreads();                       // A chunk published

    const ushort_t* bH = whi + (size_t)(c * NST) * 8192 + bOff;
    const ushort_t* bL = wlo + (size_t)(c * NST) * 8192 + bOff;
#pragma unroll 4
    for (int s = 0; s < NST; ++s) {
      short8 bh = *(const short8*)(bH + (size_t)s * 8192);
      short8 bl = *(const short8*)(bL + (size_t)s * 8192);
      const int ao = (s ^ b2) << 5;
      short8 a0h = *(const short8*)(a0P + ao);
      short8 a0l = *(const short8*)(a0P + 512 + ao);
      short8 a1h = *(const short8*)(a1P + ao);
      short8 a1l = *(const short8*)(a1P + 512 + ao);
      acc0 = __builtin_amdgcn_mfma_f32_32x32x16_bf16(a0h, bh, acc0, 0, 0, 0);
      acc0 = __builtin_amdgcn_mfma_f32_32x32x16_bf16(a0h, bl, acc0, 0, 0, 0);
      acc0 = __builtin_amdgcn_mfma_f32_32x32x16_bf16(a0l, bh, acc0, 0, 0, 0);
      acc1 = __builtin_amdgcn_mfma_f32_32x32x16_bf16(a1h, bh, acc1, 0, 0, 0);
      acc1 = __builtin_amdgcn_mfma_f32_32x32x16_bf16(a1h, bl, acc1, 0, 0, 0);
      acc1 = __builtin_amdgcn_mfma_f32_32x32x16_bf16(a1l, bh, acc1, 0, 0, 0);
    }
  }

  __syncthreads();                         // A2 dead; union reuse safe

  // ---- kh-pair accumulator reduction through LDS ----
  if (kh == 1) {
#pragma unroll
    for (int r = 0; r < 16; ++r) {
      sm.u.ep.red[eg][0][r][lane] = acc0[r];
      sm.u.ep.red[eg][1][r][lane] = acc1[r];
    }
  }
  __syncthreads();

  // ---- kh==0 waves: total score -> biased value -> val[row][expert] ----
  if (kh == 0) {
    const int myE = eg * 32 + m;
    const float myBias = sm.bias[myE];
#pragma unroll
    for (int b = 0; b < 2; ++b) {
#pragma unroll
      for (int reg = 0; reg < 16; ++reg) {
        const int row_local = b * 32 + (reg & 3) + 8 * (reg >> 2) + 4 * hf;
        float s = (b ? acc1[reg] : acc0[reg]) +
                  sm.u.ep.red[eg][b][reg][lane];
        float v = sqrtf(fmaxf(s, 0.f) + log1pf(expf(-fabsf(s)))) + myBias;
        sm.u.ep.val[row_local * VST + myE] = v;
      }
    }
  }
  __syncthreads();

  // ---- parallel top-8: 16 threads/row, sort networks + xor-merge ----
  {
    const int r  = t >> 4;        // row 0..63
    const int sl = t & 15;        // 16-expert slice
    const float* vr = &sm.u.ep.val[r * VST + sl * 16];
    u64 k[16];
#pragma unroll
    for (int j = 0; j < 4; ++j) {
      float4 q4 = *(const float4*)&vr[j * 4];
      k[j * 4 + 0] = mkkey(q4.x, sl * 16 + j * 4 + 0);
      k[j * 4 + 1] = mkkey(q4.y, sl * 16 + j * 4 + 1);
      k[j * 4 + 2] = mkkey(q4.z, sl * 16 + j * 4 + 2);
      k[j * 4 + 3] = mkkey(q4.w, sl * 16 + j * 4 + 3);
    }
    SORT8(0);                     // k[0..7]  descending
    SORT8(8);                     // k[8..15] descending
    // top-8 of 16: bitonic partner-max then re-sort
    k[0] = kmax(k[0], k[15]); k[1] = kmax(k[1], k[14]);
    k[2] = kmax(k[2], k[13]); k[3] = kmax(k[3], k[12]);
    k[4] = kmax(k[4], k[11]); k[5] = kmax(k[5], k[10]);
    k[6] = kmax(k[6], k[9]);  k[7] = kmax(k[7], k[8]);
    BMERGE8;
    // merge across the 16 threads of this row (xor butterflies)
#pragma unroll
    for (int off = 1; off < 16; off <<= 1) {
      u64 o[8];
#pragma unroll
      for (int i = 0; i < 8; ++i) o[i] = __shfl_xor(k[i], off, 64);
      k[0] = kmax(k[0], o[7]); k[1] = kmax(k[1], o[6]);
      k[2] = kmax(k[2], o[5]); k[3] = kmax(k[3], o[4]);
      k[4] = kmax(k[4], o[3]); k[5] = kmax(k[5], o[2]);
      k[6] = kmax(k[6], o[1]); k[7] = kmax(k[7], o[0]);
      BMERGE8;
    }

    if (sl == 0) {
      float tv[8]; int ti[8];
#pragma unroll
      for (int i = 0; i < 8; ++i) { tv[i] = keyval(k[i]); ti[i] = keyidx(k[i]); }
      bool flag = false;
#pragma unroll
      for (int i = 0; i < 7; ++i) flag |= (tv[i] - tv[i + 1] < TAU);
      const int grow = row0 + r;
      if (!flag) {
        float og[6], ssum = 0.f;
#pragma unroll
        for (int i = 0; i < 6; ++i) { og[i] = tv[i] - sm.bias[ti[i]]; ssum += og[i]; }
        const float sc = 1.5f / ssum;
#pragma unroll
        for (int i = 0; i < 6; ++i) {
          outw[(size_t)grow * TK + i] = og[i] * sc;
          outi[(size_t)grow * TK + i] = (float)ti[i];
        }
      } else {
        int slot = atomicAdd(&sm.nflag, 1);
        sm.flagrow[slot] = grow;
#pragma unroll
        for (int i = 0; i < 8; ++i) sm.flagid[slot][i] = ti[i];
      }
    }
  }
  __syncthreads();

  // ---- exact fp64 rescue for flagged rows (expected <1/block) ----
  const int nf = sm.nflag;
  for (int f = 0; f < nf; ++f) {
    const int grow = sm.flagrow[f];
    if (wv < 8) {
      const int e = sm.flagid[f][wv];
      double accd = 0.0;
      const float4* xr = x4 + (size_t)grow * D4 + lane * 16;
      const float4* wr = w4 + (size_t)e    * D4 + lane * 16;
#pragma unroll
      for (int i = 0; i < 16; ++i) {
        float4 xv = xr[i], wl = wr[i];
        accd = fma((double)xv.x, (double)wl.x, accd);
        accd = fma((double)xv.y, (double)wl.y, accd);
        accd = fma((double)xv.z, (double)wl.z, accd);
        accd = fma((double)xv.w, (double)wl.w, accd);
      }
#pragma unroll
      for (int off = 1; off < 64; off <<= 1)
        accd += __shfl_xor(accd, off, 64);
      if (lane == 0) {
        double sp = fmax(accd, 0.0) + log1p(exp(-fabs(accd)));
        sm.exact[wv] = sqrt(sp);   // orig (unbiased) score
      }
    }
    __syncthreads();
    if (t == 0) {
      double ov[8]; int oid[8], ordr[8];
      for (int i = 0; i < 8; ++i) { ov[i] = sm.exact[i]; oid[i] = sm.flagid[f][i]; ordr[i] = i; }
      for (int i = 0; i < 6; ++i) {
        int b = i;
        for (int j = i + 1; j < 8; ++j) {
          double bj = ov[ordr[j]] + (double)sm.bias[oid[ordr[j]]];
          double bb = ov[ordr[b]] + (double)sm.bias[oid[ordr[b]]];
          if (bj > bb || (bj == bb && oid[ordr[j]] < oid[ordr[b]])) b = j;
        }
        int tmp = ordr[i]; ordr[i] = ordr[b]; ordr[b] = tmp;
      }
      double ssum = 0.0;
      for (int i = 0; i < 6; ++i) ssum += ov[ordr[i]];
      double sc = 1.5 / ssum;
      for (int i = 0; i < 6; ++i) {
        outw[(size_t)grow * TK + i] = (float)(ov[ordr[i]] * sc);
        outi[(size_t)grow * TK + i] = (float)oid[ordr[i]];
      }
    }
    __syncthreads();
  }
}

extern "C" void kernel_launch(void* const* d_in, const int* in_sizes, int n_in,
                              void* d_out, int out_size, void* d_ws, size_t ws_size,
                              hipStream_t stream) {
  const float* x = (const float*)d_in[0];
  const float* w = (const float*)d_in[1];
  const float* b = (const float*)d_in[2];
  float* out  = (float*)d_out;
  const int N = in_sizes[0] / D;          // 16384

  ushort_t* whi = (ushort_t*)d_ws;                      // E*D bf16 = 2 MB (tile-major)
  ushort_t* wlo = whi + (size_t)E * D;                  // +2 MB

  float* outw = out;                      // [N,6] weights
  float* outi = out + (size_t)N * TK;     // [N,6] indices (as float)

  hipLaunchKernelGGL(conv_w, dim3(E * D / 4 / 256), dim3(256), 0, stream,
                     w, whi, wlo);
  hipLaunchKernelGGL(gate_kernel, dim3(N / BM), dim3(NT), 0, stream,
                     x, w, b, whi, wlo, outw, outi);
}